// Round 12
// baseline (7248.341 us; speedup 1.0000x reference)
//
#include <hip/hip_runtime.h>
#include <math.h>

// Matrix-Tree marginals: probs[b,i,j] = A[i,j]*(X[i-1,i-1] - (j>=1 ? X[j-1,i-1] : 0))
// X = inv(M) via blocked in-place Gauss-Jordan (4 panel steps of 64, SDD -> no pivoting).
// Round-12: exact round-8 k_step (570us, best validated) + T3-minimal pipelined staging
// (ping-pong 3-double register prestage per chunk -- R11's 48-double version spilled to
// scratch, FETCH 65MB->3GB; this stays ~120 VGPR) + fused transpose/epilogue (k_diag +
// k_xtepi replace k_xt + k_epi2, saving the 134MB f32 out round-trip).
// ws (doubles): M[B][256][256] | mb[B] | nb[B](int) | Dg[B][256]; partial aliases Dg.

#define S 256
#define BB 256

__device__ __forceinline__ int rowmap(int lr, int kb) {   // local 0..191 -> global row skipping panel kb
    int rt = lr >> 6;
    int rb = rt + (rt >= kb ? 1 : 0);
    return rb * 64 + (lr & 63);
}

// ---------------- kernel 1a: dense max over each batch's full 256x256 score matrix ----------
__global__ __launch_bounds__(256) void k_max(const float* __restrict__ sc,
                                             float* __restrict__ partial) {
    int b = blockIdx.y, rg = blockIdx.x;                 // 8 row-groups of 32 rows
    const float4* p4 = (const float4*)(sc + (size_t)b * S * S + rg * 8192);
    int tid = threadIdx.x;
    float4 v[8];
    #pragma unroll
    for (int it = 0; it < 8; ++it) v[it] = p4[tid + 256 * it];
    float m = -1e30f;
    #pragma unroll
    for (int it = 0; it < 8; ++it)
        m = fmaxf(m, fmaxf(fmaxf(v[it].x, v[it].y), fmaxf(v[it].z, v[it].w)));
    for (int off = 32; off > 0; off >>= 1) m = fmaxf(m, __shfl_down(m, off));
    __shared__ float sm[4];
    if ((tid & 63) == 0) sm[tid >> 6] = m;
    __syncthreads();
    if (tid == 0) partial[b * 8 + rg] = fmaxf(fmaxf(sm[0], sm[1]), fmaxf(sm[2], sm[3]));
}

// ---------------- kernel 1b: per-batch n (mask count) + combine partial maxima --------------
__global__ void k_n(const unsigned char* __restrict__ mk, const float* __restrict__ partial,
                    double* __restrict__ mb, int* __restrict__ nb) {
    int b = blockIdx.x, j = threadIdx.x;
    __shared__ int shc[4];

    const unsigned int* mw = (const unsigned int*)mk;    // sniff mask dtype
    unsigned int w0 = mw[0], w1 = mw[1];
    int mode = (w0 != 0u) ? 0 : ((w1 != 0u) ? 1 : 2);

    int c;
    if (mode == 0)      c = (mk[(size_t)b * S + j] != 0);
    else if (mode == 1) c = (((const int*)mk)[(size_t)b * S + j] != 0);
    else                c = (((const long long*)mk)[(size_t)b * S + j] != 0LL);

    int lane = j & 63, wid = j >> 6;
    int cs = c;
    for (int off = 32; off > 0; off >>= 1) cs += __shfl_down(cs, off);
    if (lane == 0) shc[wid] = cs;
    __syncthreads();
    if (j == 0) {
        nb[b] = shc[0] + shc[1] + shc[2] + shc[3];
        float mm = partial[b * 8];
        #pragma unroll
        for (int q = 1; q < 8; ++q) mm = fmaxf(mm, partial[b * 8 + q]);
        mb[b] = (double)mm;
    }
}

// ---------------- kernel 2: build padded M (f64, expf), 4 rows per block --------------------
__global__ __launch_bounds__(256) void k_build(const float* __restrict__ sc,
                                               const double* __restrict__ mb,
                                               const int* __restrict__ nb,
                                               double* __restrict__ Mg) {
    int b = blockIdx.y;
    int wid = threadIdx.x >> 6, lane = threadIdx.x & 63;
    int p = blockIdx.x * 4 + wid;
    int n = nb[b];
    double m = mb[b];
    __shared__ double se[4][260];
    double* Mrow = Mg + ((size_t)b * S + p) * S;
    bool act = (p < n);
    double ssum = 0.0;
    #pragma unroll
    for (int c4 = 0; c4 < 4; ++c4) {
        int j = lane + 64 * c4;
        double ev = 0.0;
        if (act && j <= n)
            ev = (double)expf((float)((double)sc[((size_t)b * S + (p + 1)) * S + j] - m));
        se[wid][j] = ev;
        ssum += ev;
    }
    for (int off = 32; off > 0; off >>= 1) ssum += __shfl_down(ssum, off);
    ssum = __shfl(ssum, 0);
    __syncthreads();                       // uniform: all 4 waves reach it
    #pragma unroll
    for (int c4 = 0; c4 < 4; ++c4) {
        int j = lane + 64 * c4;
        double v;
        if (act && j < n) v = ((j == p) ? ssum : 0.0) - se[wid][j + 1];
        else              v = (j == p) ? 1.0 : 0.0;
        Mrow[j] = v;
    }
}

// ---------------- kernel 3: fused panel step, pipelined staging -----------------------------
// Staging macros: 3-double register ping-pong per chunk (static indices only).
#define STAGE_RC(csn, RN)                                                                   \
    { _Pragma("unroll") for (int rep = 0; rep < 3; ++rep) {                                 \
          int idx = rep * 512 + tid; int sL = idx / 192, jj = idx - sL * 192;               \
          RN[rep] = M[(size_t)(kb * 64 + (csn) * 8 + sL) * S + rowmap(jj, kb)]; } }

#define STAGE_FT(hcn, FN)                                                                   \
    { _Pragma("unroll") for (int rep = 0; rep < 3; ++rep) {                                 \
          int idx = rep * 512 + tid; int kk = idx & 15, lr = idx >> 4;                      \
          FN[rep] = M[(size_t)rowmap(((hcn) >> 2) * 96 + lr, kb) * S                        \
                      + kb * 64 + ((hcn) & 3) * 16 + kk]; } }

#define P2_COMPUTE                                                                          \
    { _Pragma("unroll") for (int sL = 0; sL < 8; ++sL) {                                    \
        double2 p01 = *(const double2*)&PT[sL * 64 + 4 * ty];                               \
        double2 p23 = *(const double2*)&PT[sL * 64 + 4 * ty + 2];                           \
        double2 r0 = *(const double2*)&Rc[sL * 192 + 2 * tx];                               \
        double2 r1 = *(const double2*)&Rc[sL * 192 + 2 * tx + 64];                          \
        double2 r2 = *(const double2*)&Rc[sL * 192 + 2 * tx + 128];                         \
        ga[0][0].x = fma(p01.x, r0.x, ga[0][0].x); ga[0][0].y = fma(p01.x, r0.y, ga[0][0].y); \
        ga[0][1].x = fma(p01.x, r1.x, ga[0][1].x); ga[0][1].y = fma(p01.x, r1.y, ga[0][1].y); \
        ga[0][2].x = fma(p01.x, r2.x, ga[0][2].x); ga[0][2].y = fma(p01.x, r2.y, ga[0][2].y); \
        ga[1][0].x = fma(p01.y, r0.x, ga[1][0].x); ga[1][0].y = fma(p01.y, r0.y, ga[1][0].y); \
        ga[1][1].x = fma(p01.y, r1.x, ga[1][1].x); ga[1][1].y = fma(p01.y, r1.y, ga[1][1].y); \
        ga[1][2].x = fma(p01.y, r2.x, ga[1][2].x); ga[1][2].y = fma(p01.y, r2.y, ga[1][2].y); \
        ga[2][0].x = fma(p23.x, r0.x, ga[2][0].x); ga[2][0].y = fma(p23.x, r0.y, ga[2][0].y); \
        ga[2][1].x = fma(p23.x, r1.x, ga[2][1].x); ga[2][1].y = fma(p23.x, r1.y, ga[2][1].y); \
        ga[2][2].x = fma(p23.x, r2.x, ga[2][2].x); ga[2][2].y = fma(p23.x, r2.y, ga[2][2].y); \
        ga[3][0].x = fma(p23.y, r0.x, ga[3][0].x); ga[3][0].y = fma(p23.y, r0.y, ga[3][0].y); \
        ga[3][1].x = fma(p23.y, r1.x, ga[3][1].x); ga[3][1].y = fma(p23.y, r1.y, ga[3][1].y); \
        ga[3][2].x = fma(p23.y, r2.x, ga[3][2].x); ga[3][2].y = fma(p23.y, r2.y, ga[3][2].y); } }

#define P2_CHUNK(cs, RC, RN, DONEXT)                                                        \
    if (g == (cs)) { _Pragma("unroll") for (int u = 0; u < 8; ++u) PT[u * 64 + i] = c[u]; } \
    { _Pragma("unroll") for (int rep = 0; rep < 3; ++rep) {                                 \
          int idx = rep * 512 + tid; int sL = idx / 192, jj = idx - sL * 192;               \
          Rc[sL * 192 + jj] = RC[rep]; } }                                                  \
    if (DONEXT) STAGE_RC((cs) + 1, RN);                                                     \
    __syncthreads();                                                                        \
    P2_COMPUTE                                                                              \
    __syncthreads();

#define P3_COMPUTE(hc)                                                                      \
    { const int ckk = (hc) & 3;                                                             \
      for (int kk = 0; kk < 16; ++kk) { int kr = ckk * 16 + kk;                             \
        double2 f01 = *(const double2*)&FT[kk * 194 + 6 * ty];                              \
        double2 f23 = *(const double2*)&FT[kk * 194 + 6 * ty + 2];                          \
        double2 f45 = *(const double2*)&FT[kk * 194 + 6 * ty + 4];                          \
        _Pragma("unroll") for (int w = 0; w < 4; ++w) {                                     \
            double2 h = *(const double2*)&H[kr * 256 + 2 * tx + 64 * w];                    \
            acc[0][w].x = fma(f01.x, h.x, acc[0][w].x); acc[0][w].y = fma(f01.x, h.y, acc[0][w].y); \
            acc[1][w].x = fma(f01.y, h.x, acc[1][w].x); acc[1][w].y = fma(f01.y, h.y, acc[1][w].y); \
            acc[2][w].x = fma(f23.x, h.x, acc[2][w].x); acc[2][w].y = fma(f23.x, h.y, acc[2][w].y); \
            acc[3][w].x = fma(f23.y, h.x, acc[3][w].x); acc[3][w].y = fma(f23.y, h.y, acc[3][w].y); \
            acc[4][w].x = fma(f45.x, h.x, acc[4][w].x); acc[4][w].y = fma(f45.x, h.y, acc[4][w].y); \
            acc[5][w].x = fma(f45.y, h.x, acc[5][w].x); acc[5][w].y = fma(f45.y, h.y, acc[5][w].y); } } }

#define P3_CHUNK(hc, FC, FN, DONEXT)                                                        \
    __syncthreads();                                                                        \
    { _Pragma("unroll") for (int rep = 0; rep < 3; ++rep) {                                 \
          int idx = rep * 512 + tid; int kk = idx & 15, lr = idx >> 4;                      \
          FT[kk * 194 + lr] = FC[rep]; } }                                                  \
    if (DONEXT) STAGE_FT((hc) + 1, FN);                                                     \
    __syncthreads();                                                                        \
    P3_COMPUTE(hc)

#define ACC_ZERO                                                                            \
    { _Pragma("unroll") for (int q2 = 0; q2 < 6; ++q2)                                      \
        { _Pragma("unroll") for (int w = 0; w < 4; ++w) acc[q2][w] = double2{0.0, 0.0}; } }

#define P3_EPI(half)                                                                        \
    { _Pragma("unroll") for (int q2 = 0; q2 < 6; ++q2) {                                    \
        size_t row = (size_t)rowmap((half) * 96 + 6 * ty + q2, kb) * S;                     \
        _Pragma("unroll") for (int w = 0; w < 4; ++w) { int j0 = 2 * tx + 64 * w;           \
            if (w == kb) { *(double2*)&M[row + j0] = double2{-acc[q2][w].x, -acc[q2][w].y}; } \
            else { double2 old = *(const double2*)&M[row + j0];                             \
                   *(double2*)&M[row + j0] = double2{old.x - acc[q2][w].x, old.y - acc[q2][w].y}; } } } }

__global__ __launch_bounds__(512) void k_step(double* __restrict__ Mg, int kb) {
    int b = blockIdx.x;
    double* M = Mg + (size_t)b * S * S;
    int tid = threadIdx.x;
    __shared__ double H[64 * 256];     // [G | Pinv] by GLOBAL column index, rows = pivot rows
    __shared__ double SCR[3104];       // union: GJ bufs (256) | PT(512)+Rc(1536) | FT 16x194(3104)

    int i = tid >> 3, g = tid & 7, c0 = g << 3;   // row i, col group g (8 cols)

    // ---- diag block row fragment (phase 1) ----
    double c[8];
    {
        const double* src = M + (size_t)(kb * 64 + i) * S + kb * 64 + c0;
        #pragma unroll
        for (int m2 = 0; m2 < 4; ++m2) {
            double2 t = *(const double2*)(src + 2 * m2);
            c[2 * m2] = t.x; c[2 * m2 + 1] = t.y;
        }
    }
    // ---- prestage first Rc chunk and first FT chunk (drain under the GJ chain) ----
    double rA[3], rB[3], fA[3], fB[3];
    STAGE_RC(0, rA);
    STAGE_FT(0, fA);

    // ---- phase 1: register GJ on the 64x64 diag block ----
    double* rbuf = SCR;          // [2][64]
    double* cbuf = SCR + 128;    // [2][64]
    if (i == 0) {
        #pragma unroll
        for (int u = 0; u < 8; ++u) rbuf[c0 + u] = c[u];
    }
    if (g == 0) cbuf[i] = c[0];
    for (int k = 0; k < 64; ++k) {
        int par = k & 1;
        __syncthreads();
        double pv = rbuf[par * 64 + k];
        double f  = cbuf[par * 64 + i];
        double rk[8];
        #pragma unroll
        for (int m2 = 0; m2 < 4; ++m2) {
            double2 t = *(const double2*)&rbuf[par * 64 + c0 + 2 * m2];
            rk[2 * m2] = t.x; rk[2 * m2 + 1] = t.y;
        }
        double pivinv = 1.0 / pv;
        int kg = k >> 3, ks = k & 7;
        if (i == k) {
            #pragma unroll
            for (int u = 0; u < 8; ++u)
                c[u] = ((g == kg) && (u == ks)) ? pivinv : c[u] * pivinv;
        } else {
            double gm = f * pivinv;
            #pragma unroll
            for (int u = 0; u < 8; ++u)
                c[u] = ((g == kg) && (u == ks)) ? (-gm) : fma(-gm, rk[u], c[u]);
        }
        int k1 = k + 1;
        if (k1 < 64) {
            if (i == k1) {
                #pragma unroll
                for (int u = 0; u < 8; ++u) rbuf[(par ^ 1) * 64 + c0 + u] = c[u];
            }
            if (g == (k1 >> 3)) cbuf[(par ^ 1) * 64 + i] = c[k1 & 7];
        }
    }
    __syncthreads();   // GJ done; SCR reusable. Threads hold Pinv[i][c0..c0+7] in c[].

    // ---- phase 2: G = Pinv * R_old (pipelined chunks), G+Pinv -> H ----
    int tx = tid & 31, ty = tid >> 5;    // ty 0..15
    double* PT = SCR;                    // PT[sL][t] = Pinv[t][cs*8+sL]   [8][64]
    double* Rc = SCR + 512;              // Rc[sL][j] = R_old[cs*8+sL][j]  [8][192]
    double2 ga[4][3];
    #pragma unroll
    for (int r = 0; r < 4; ++r)
        #pragma unroll
        for (int q = 0; q < 3; ++q) ga[r][q] = double2{0.0, 0.0};

    P2_CHUNK(0, rA, rB, 1) P2_CHUNK(1, rB, rA, 1) P2_CHUNK(2, rA, rB, 1) P2_CHUNK(3, rB, rA, 1)
    P2_CHUNK(4, rA, rB, 1) P2_CHUNK(5, rB, rA, 1) P2_CHUNK(6, rA, rB, 1) P2_CHUNK(7, rB, rA, 0)

    // G -> H (global-column indexing), Pinv -> H pivot cols
    #pragma unroll
    for (int r = 0; r < 4; ++r)
        #pragma unroll
        for (int q = 0; q < 3; ++q) {
            int col = rowmap(2 * tx + 64 * q, kb);
            *(double2*)&H[(4 * ty + r) * 256 + col] = ga[r][q];
        }
    #pragma unroll
    for (int u = 0; u < 8; ++u) H[i * 256 + kb * 64 + c0 + u] = c[u];
    __syncthreads();                     // H complete

    // H -> M pivot rows (early: global writes drain under the update phase)
    #pragma unroll
    for (int rep = 0; rep < 16; ++rep) {
        int idx = rep * 512 + tid;
        int row = idx >> 7, col2 = idx & 127;
        *(double2*)&M[(size_t)(kb * 64 + row) * S + 2 * col2] =
            *(const double2*)&H[row * 256 + 2 * col2];
    }

    // ---- phase 3: interior RMW M -= F*H ; pivot cols <- -F*Pinv. Pipelined FT chunks. ----
    double* FT = SCR;                    // FT[kk][lr] = F[half*96+lr][ck*16+kk]  [16][194]
    double2 acc[6][4];
    ACC_ZERO
    P3_CHUNK(0, fA, fB, 1) P3_CHUNK(1, fB, fA, 1) P3_CHUNK(2, fA, fB, 1) P3_CHUNK(3, fB, fA, 1)
    P3_EPI(0)
    ACC_ZERO
    P3_CHUNK(4, fA, fB, 1) P3_CHUNK(5, fB, fA, 1) P3_CHUNK(6, fA, fB, 1) P3_CHUNK(7, fB, fA, 0)
    P3_EPI(1)
}

// ---------------- kernel 4a: diag extract + row-0/col-0 epilogue ----------------------------
__global__ __launch_bounds__(256) void k_diag(const double* __restrict__ Mg,
                                              const float* __restrict__ sc,
                                              const double* __restrict__ mb,
                                              const int* __restrict__ nb,
                                              double* __restrict__ Dg,
                                              float* __restrict__ out) {
    int b = blockIdx.x, t = threadIdx.x;
    const double* M = Mg + (size_t)b * S * S;
    __shared__ double sd[256];
    double d = M[(size_t)t * S + t];
    sd[t] = d;
    Dg[(size_t)b * S + t] = d;
    out[(size_t)b * S * S + t] = 0.0f;            // row 0
    __syncthreads();
    int n = nb[b];
    float m = (float)mb[b];
    if (t >= 1) {                                 // col 0, rows 1..255
        float v = 0.0f;
        if (t <= n) {
            double A = (double)expf(sc[((size_t)b * S + t) * S + 0] - m);
            v = (float)(A * sd[t - 1]);
        }
        out[((size_t)b * S + t) * S + 0] = v;
    }
}

// ---------------- kernel 4b: fused transpose + epilogue (i,j >= 1) --------------------------
// Tile (r,c): stages X[64r..][64c..] into LDS (f32), writes out[orow][ocol] with
// orow=64c+qq+1, ocol=64r+pp+1: v = A(orow,ocol) * (X[orow-1][orow-1] - X[ocol-1][orow-1]).
__global__ __launch_bounds__(256) void k_xtepi(const double* __restrict__ Mg,
                                               const float* __restrict__ sc,
                                               const double* __restrict__ mb,
                                               const int* __restrict__ nb,
                                               const double* __restrict__ Dg,
                                               float* __restrict__ out) {
    int b = blockIdx.y, t = blockIdx.x;
    int r = t & 3, c = t >> 2;
    const double* M = Mg + (size_t)b * S * S;
    __shared__ float L[64][65];
    __shared__ double sdg[64];
    int tid = threadIdx.x;
    int cc = tid & 63;
    #pragma unroll
    for (int rep = 0; rep < 16; ++rep) {
        int rr = rep * 4 + (tid >> 6);
        L[rr][cc] = (float)M[(size_t)(64 * r + rr) * S + 64 * c + cc];
    }
    if (tid < 64) sdg[tid] = Dg[(size_t)b * S + 64 * c + tid];
    __syncthreads();
    int n = nb[b];
    float m = (float)mb[b];
    int pp = tid & 63;
    #pragma unroll
    for (int rep = 0; rep < 16; ++rep) {
        int qq = rep * 4 + (tid >> 6);
        int orow = 64 * c + qq + 1, ocol = 64 * r + pp + 1;
        if (orow < 256 && ocol < 256) {
            float v = 0.0f;
            if (orow <= n && ocol <= n) {
                double A = (double)expf(sc[((size_t)b * S + orow) * S + ocol] - m);
                v = (float)(A * (sdg[qq] - (double)L[pp][qq]));
            }
            out[((size_t)b * S + orow) * S + ocol] = v;
        }
    }
}

// ---------------- launcher ----------------
extern "C" void kernel_launch(void* const* d_in, const int* in_sizes, int n_in,
                              void* d_out, int out_size, void* d_ws, size_t ws_size,
                              hipStream_t stream) {
    (void)in_sizes; (void)n_in; (void)out_size; (void)ws_size;
    const float* sc = (const float*)d_in[0];
    const unsigned char* mk = (const unsigned char*)d_in[1];
    double* ws = (double*)d_ws;

    double* M  = ws;                                 // B*256*256
    double* mb = M + (size_t)BB * S * S;             // B doubles
    int*    nb = (int*)(mb + BB);                    // B ints
    double* Dg = mb + 2 * BB;                        // B*256 doubles
    float*  partial = (float*)Dg;                    // aliases Dg (consumed before Dg written)
    float*  out = (float*)d_out;

    k_max<<<dim3(8, BB), 256, 0, stream>>>(sc, partial);
    k_n<<<BB, 256, 0, stream>>>(mk, partial, mb, nb);
    k_build<<<dim3(64, BB), 256, 0, stream>>>(sc, mb, nb, M);
    for (int kb = 0; kb < 4; ++kb)
        k_step<<<BB, 512, 0, stream>>>(M, kb);
    k_diag<<<BB, 256, 0, stream>>>(M, sc, mb, nb, Dg, out);
    k_xtepi<<<dim3(16, BB), 256, 0, stream>>>(M, sc, mb, nb, Dg, out);
}

// Round 13
// 549.318 us; speedup vs baseline: 13.1952x; 13.1952x over previous
//
#include <hip/hip_runtime.h>
#include <math.h>

// Matrix-Tree marginals: probs[b,i,j] = A[i,j]*(X[i-1,i-1] - (j>=1 ? X[j-1,i-1] : 0))
// X = inv(M) via blocked in-place Gauss-Jordan (4 panel steps of 64, SDD -> no pivoting).
// Round-13: k_step reverted byte-for-byte to round-8's validated version (96 VGPR, no
// prestage -- R11/R12's register prestage tipped the VGPR cliff: acc[] spilled to scratch,
// FETCH 65MB->3GB, 12x slowdown). Keeps R12's validated epilogue fusion (k_diag + k_xtepi,
// saving the 134MB f32 out round-trip of k_xt+k_epi2).
// ws (doubles): M[B][256][256] | mb[B] | nb[B](int) | Dg[B][256]; partial aliases Dg.

#define S 256
#define BB 256

__device__ __forceinline__ int rowmap(int lr, int kb) {   // local 0..191 -> global row skipping panel kb
    int rt = lr >> 6;
    int rb = rt + (rt >= kb ? 1 : 0);
    return rb * 64 + (lr & 63);
}

// ---------------- kernel 1a: dense max over each batch's full 256x256 score matrix ----------
// (marginals are exactly invariant to the stabilizer m, so global max is as good as masked max)
__global__ __launch_bounds__(256) void k_max(const float* __restrict__ sc,
                                             float* __restrict__ partial) {
    int b = blockIdx.y, rg = blockIdx.x;                 // 8 row-groups of 32 rows
    const float4* p4 = (const float4*)(sc + (size_t)b * S * S + rg * 8192);
    int tid = threadIdx.x;
    float4 v[8];
    #pragma unroll
    for (int it = 0; it < 8; ++it) v[it] = p4[tid + 256 * it];
    float m = -1e30f;
    #pragma unroll
    for (int it = 0; it < 8; ++it)
        m = fmaxf(m, fmaxf(fmaxf(v[it].x, v[it].y), fmaxf(v[it].z, v[it].w)));
    for (int off = 32; off > 0; off >>= 1) m = fmaxf(m, __shfl_down(m, off));
    __shared__ float sm[4];
    if ((tid & 63) == 0) sm[tid >> 6] = m;
    __syncthreads();
    if (tid == 0) partial[b * 8 + rg] = fmaxf(fmaxf(sm[0], sm[1]), fmaxf(sm[2], sm[3]));
}

// ---------------- kernel 1b: per-batch n (mask count) + combine partial maxima --------------
__global__ void k_n(const unsigned char* __restrict__ mk, const float* __restrict__ partial,
                    double* __restrict__ mb, int* __restrict__ nb) {
    int b = blockIdx.x, j = threadIdx.x;
    __shared__ int shc[4];

    const unsigned int* mw = (const unsigned int*)mk;    // sniff mask dtype
    unsigned int w0 = mw[0], w1 = mw[1];
    int mode = (w0 != 0u) ? 0 : ((w1 != 0u) ? 1 : 2);

    int c;
    if (mode == 0)      c = (mk[(size_t)b * S + j] != 0);
    else if (mode == 1) c = (((const int*)mk)[(size_t)b * S + j] != 0);
    else                c = (((const long long*)mk)[(size_t)b * S + j] != 0LL);

    int lane = j & 63, wid = j >> 6;
    int cs = c;
    for (int off = 32; off > 0; off >>= 1) cs += __shfl_down(cs, off);
    if (lane == 0) shc[wid] = cs;
    __syncthreads();
    if (j == 0) {
        nb[b] = shc[0] + shc[1] + shc[2] + shc[3];
        float mm = partial[b * 8];
        #pragma unroll
        for (int q = 1; q < 8; ++q) mm = fmaxf(mm, partial[b * 8 + q]);
        mb[b] = (double)mm;
    }
}

// ---------------- kernel 2: build padded M (f64, expf), 4 rows per block --------------------
__global__ __launch_bounds__(256) void k_build(const float* __restrict__ sc,
                                               const double* __restrict__ mb,
                                               const int* __restrict__ nb,
                                               double* __restrict__ Mg) {
    int b = blockIdx.y;
    int wid = threadIdx.x >> 6, lane = threadIdx.x & 63;
    int p = blockIdx.x * 4 + wid;
    int n = nb[b];
    double m = mb[b];
    __shared__ double se[4][260];
    double* Mrow = Mg + ((size_t)b * S + p) * S;
    bool act = (p < n);
    double ssum = 0.0;
    #pragma unroll
    for (int c4 = 0; c4 < 4; ++c4) {
        int j = lane + 64 * c4;
        double ev = 0.0;
        if (act && j <= n)
            ev = (double)expf((float)((double)sc[((size_t)b * S + (p + 1)) * S + j] - m));
        se[wid][j] = ev;
        ssum += ev;
    }
    for (int off = 32; off > 0; off >>= 1) ssum += __shfl_down(ssum, off);
    ssum = __shfl(ssum, 0);
    __syncthreads();                       // uniform: all 4 waves reach it
    #pragma unroll
    for (int c4 = 0; c4 < 4; ++c4) {
        int j = lane + 64 * c4;
        double v;
        if (act && j < n) v = ((j == p) ? ssum : 0.0) - se[wid][j + 1];
        else              v = (j == p) ? 1.0 : 0.0;
        Mrow[j] = v;
    }
}

// ---------------- kernel 3: fused panel step (GJ + rowG + interior + colP) ------------------
// Byte-identical to round-8's validated k_step (96 VGPR, no prestage).
__global__ __launch_bounds__(512) void k_step(double* __restrict__ Mg, int kb) {
    int b = blockIdx.x;
    double* M = Mg + (size_t)b * S * S;
    int tid = threadIdx.x;
    __shared__ double H[64 * 256];     // [G | Pinv] by GLOBAL column index, rows = pivot rows
    __shared__ double SCR[3104];       // union: GJ bufs (256) | PT(512)+Rc(1536) | FT 16x194(3104)

    // ---- phase 1: register GJ on the 64x64 diag block ----
    int i = tid >> 3, g = tid & 7, c0 = g << 3;   // row i, col group g (8 cols)
    double c[8];
    {
        const double* src = M + (size_t)(kb * 64 + i) * S + kb * 64 + c0;
        #pragma unroll
        for (int m2 = 0; m2 < 4; ++m2) {
            double2 t = *(const double2*)(src + 2 * m2);
            c[2 * m2] = t.x; c[2 * m2 + 1] = t.y;
        }
    }
    double* rbuf = SCR;          // [2][64]
    double* cbuf = SCR + 128;    // [2][64]
    if (i == 0) {
        #pragma unroll
        for (int u = 0; u < 8; ++u) rbuf[c0 + u] = c[u];
    }
    if (g == 0) cbuf[i] = c[0];
    for (int k = 0; k < 64; ++k) {
        int par = k & 1;
        __syncthreads();
        double pv = rbuf[par * 64 + k];
        double f  = cbuf[par * 64 + i];
        double rk[8];
        #pragma unroll
        for (int m2 = 0; m2 < 4; ++m2) {
            double2 t = *(const double2*)&rbuf[par * 64 + c0 + 2 * m2];
            rk[2 * m2] = t.x; rk[2 * m2 + 1] = t.y;
        }
        double pivinv = 1.0 / pv;
        int kg = k >> 3, ks = k & 7;
        if (i == k) {
            #pragma unroll
            for (int u = 0; u < 8; ++u)
                c[u] = ((g == kg) && (u == ks)) ? pivinv : c[u] * pivinv;
        } else {
            double gm = f * pivinv;
            #pragma unroll
            for (int u = 0; u < 8; ++u)
                c[u] = ((g == kg) && (u == ks)) ? (-gm) : fma(-gm, rk[u], c[u]);
        }
        int k1 = k + 1;
        if (k1 < 64) {
            if (i == k1) {
                #pragma unroll
                for (int u = 0; u < 8; ++u) rbuf[(par ^ 1) * 64 + c0 + u] = c[u];
            }
            if (g == (k1 >> 3)) cbuf[(par ^ 1) * 64 + i] = c[k1 & 7];
        }
    }
    __syncthreads();   // GJ done; SCR reusable. Threads hold Pinv[i][c0..c0+7] in c[].

    // ---- phase 2: G = Pinv * R_old  (8 chunks of 8 k-rows), G+Pinv -> H ----
    int tx = tid & 31, ty = tid >> 5;    // ty 0..15
    double* PT = SCR;                    // PT[sL][t] = Pinv[t][cs*8+sL]   [8][64]
    double* Rc = SCR + 512;              // Rc[sL][j] = R_old[cs*8+sL][j]  [8][192]
    double2 ga[4][3];
    #pragma unroll
    for (int r = 0; r < 4; ++r)
        #pragma unroll
        for (int q = 0; q < 3; ++q) ga[r][q] = double2{0.0, 0.0};

    for (int cs = 0; cs < 8; ++cs) {
        if (g == cs) {
            #pragma unroll
            for (int u = 0; u < 8; ++u) PT[u * 64 + i] = c[u];
        }
        #pragma unroll
        for (int rep = 0; rep < 3; ++rep) {
            int idx = rep * 512 + tid;
            int sL = idx / 192, jj = idx - sL * 192;
            Rc[sL * 192 + jj] = M[(size_t)(kb * 64 + cs * 8 + sL) * S + rowmap(jj, kb)];
        }
        __syncthreads();
        #pragma unroll
        for (int sL = 0; sL < 8; ++sL) {
            double2 p01 = *(const double2*)&PT[sL * 64 + 4 * ty];
            double2 p23 = *(const double2*)&PT[sL * 64 + 4 * ty + 2];
            double2 r0 = *(const double2*)&Rc[sL * 192 + 2 * tx];
            double2 r1 = *(const double2*)&Rc[sL * 192 + 2 * tx + 64];
            double2 r2 = *(const double2*)&Rc[sL * 192 + 2 * tx + 128];
            ga[0][0].x = fma(p01.x, r0.x, ga[0][0].x); ga[0][0].y = fma(p01.x, r0.y, ga[0][0].y);
            ga[0][1].x = fma(p01.x, r1.x, ga[0][1].x); ga[0][1].y = fma(p01.x, r1.y, ga[0][1].y);
            ga[0][2].x = fma(p01.x, r2.x, ga[0][2].x); ga[0][2].y = fma(p01.x, r2.y, ga[0][2].y);
            ga[1][0].x = fma(p01.y, r0.x, ga[1][0].x); ga[1][0].y = fma(p01.y, r0.y, ga[1][0].y);
            ga[1][1].x = fma(p01.y, r1.x, ga[1][1].x); ga[1][1].y = fma(p01.y, r1.y, ga[1][1].y);
            ga[1][2].x = fma(p01.y, r2.x, ga[1][2].x); ga[1][2].y = fma(p01.y, r2.y, ga[1][2].y);
            ga[2][0].x = fma(p23.x, r0.x, ga[2][0].x); ga[2][0].y = fma(p23.x, r0.y, ga[2][0].y);
            ga[2][1].x = fma(p23.x, r1.x, ga[2][1].x); ga[2][1].y = fma(p23.x, r1.y, ga[2][1].y);
            ga[2][2].x = fma(p23.x, r2.x, ga[2][2].x); ga[2][2].y = fma(p23.x, r2.y, ga[2][2].y);
            ga[3][0].x = fma(p23.y, r0.x, ga[3][0].x); ga[3][0].y = fma(p23.y, r0.y, ga[3][0].y);
            ga[3][1].x = fma(p23.y, r1.x, ga[3][1].x); ga[3][1].y = fma(p23.y, r1.y, ga[3][1].y);
            ga[3][2].x = fma(p23.y, r2.x, ga[3][2].x); ga[3][2].y = fma(p23.y, r2.y, ga[3][2].y);
        }
        __syncthreads();                 // inner reads done before next chunk restages SCR
    }
    // G -> H (global-column indexing), Pinv -> H pivot cols
    #pragma unroll
    for (int r = 0; r < 4; ++r)
        #pragma unroll
        for (int q = 0; q < 3; ++q) {
            int col = rowmap(2 * tx + 64 * q, kb);
            *(double2*)&H[(4 * ty + r) * 256 + col] = ga[r][q];
        }
    #pragma unroll
    for (int u = 0; u < 8; ++u) H[i * 256 + kb * 64 + c0 + u] = c[u];
    __syncthreads();                     // H complete

    // H -> M pivot rows (early: global writes drain under the update phase)
    #pragma unroll
    for (int rep = 0; rep < 16; ++rep) {
        int idx = rep * 512 + tid;
        int row = idx >> 7, col2 = idx & 127;
        *(double2*)&M[(size_t)(kb * 64 + row) * S + 2 * col2] =
            *(const double2*)&H[row * 256 + 2 * col2];
    }

    // ---- phase 3: update. interior RMW M -= F*H ; pivot cols <- -F*Pinv. Two 96-row halves.
    double* FT = SCR;                    // FT[kk][lr] = F[half*96+lr][ck*16+kk]  [16][194]
    for (int half = 0; half < 2; ++half) {
        double2 acc[6][4];
        #pragma unroll
        for (int q = 0; q < 6; ++q)
            #pragma unroll
            for (int w = 0; w < 4; ++w) acc[q][w] = double2{0.0, 0.0};

        for (int ck = 0; ck < 4; ++ck) {
            __syncthreads();             // prior SCR reads done
            #pragma unroll
            for (int rep = 0; rep < 3; ++rep) {
                int idx = rep * 512 + tid;
                int kk = idx & 15, lr = idx >> 4;    // lr 0..95
                FT[kk * 194 + lr] =
                    M[(size_t)rowmap(half * 96 + lr, kb) * S + kb * 64 + ck * 16 + kk];
            }
            __syncthreads();
            for (int kk = 0; kk < 16; ++kk) {
                int kr = ck * 16 + kk;
                double2 f01 = *(const double2*)&FT[kk * 194 + 6 * ty];
                double2 f23 = *(const double2*)&FT[kk * 194 + 6 * ty + 2];
                double2 f45 = *(const double2*)&FT[kk * 194 + 6 * ty + 4];
                #pragma unroll
                for (int w = 0; w < 4; ++w) {
                    double2 h = *(const double2*)&H[kr * 256 + 2 * tx + 64 * w];
                    acc[0][w].x = fma(f01.x, h.x, acc[0][w].x); acc[0][w].y = fma(f01.x, h.y, acc[0][w].y);
                    acc[1][w].x = fma(f01.y, h.x, acc[1][w].x); acc[1][w].y = fma(f01.y, h.y, acc[1][w].y);
                    acc[2][w].x = fma(f23.x, h.x, acc[2][w].x); acc[2][w].y = fma(f23.x, h.y, acc[2][w].y);
                    acc[3][w].x = fma(f23.y, h.x, acc[3][w].x); acc[3][w].y = fma(f23.y, h.y, acc[3][w].y);
                    acc[4][w].x = fma(f45.x, h.x, acc[4][w].x); acc[4][w].y = fma(f45.x, h.y, acc[4][w].y);
                    acc[5][w].x = fma(f45.y, h.x, acc[5][w].x); acc[5][w].y = fma(f45.y, h.y, acc[5][w].y);
                }
            }
        }
        // epilogue: own rows only (all F reads for this half are complete)
        #pragma unroll
        for (int q = 0; q < 6; ++q) {
            size_t row = (size_t)rowmap(half * 96 + 6 * ty + q, kb) * S;
            #pragma unroll
            for (int w = 0; w < 4; ++w) {
                int j0 = 2 * tx + 64 * w;
                if (w == kb) {
                    *(double2*)&M[row + j0] = double2{-acc[q][w].x, -acc[q][w].y};
                } else {
                    double2 old = *(const double2*)&M[row + j0];
                    *(double2*)&M[row + j0] = double2{old.x - acc[q][w].x, old.y - acc[q][w].y};
                }
            }
        }
    }
}

// ---------------- kernel 4a: diag extract + row-0/col-0 epilogue ----------------------------
__global__ __launch_bounds__(256) void k_diag(const double* __restrict__ Mg,
                                              const float* __restrict__ sc,
                                              const double* __restrict__ mb,
                                              const int* __restrict__ nb,
                                              double* __restrict__ Dg,
                                              float* __restrict__ out) {
    int b = blockIdx.x, t = threadIdx.x;
    const double* M = Mg + (size_t)b * S * S;
    __shared__ double sd[256];
    double d = M[(size_t)t * S + t];
    sd[t] = d;
    Dg[(size_t)b * S + t] = d;
    out[(size_t)b * S * S + t] = 0.0f;            // row 0
    __syncthreads();
    int n = nb[b];
    float m = (float)mb[b];
    if (t >= 1) {                                 // col 0, rows 1..255
        float v = 0.0f;
        if (t <= n) {
            double A = (double)expf(sc[((size_t)b * S + t) * S + 0] - m);
            v = (float)(A * sd[t - 1]);
        }
        out[((size_t)b * S + t) * S + 0] = v;
    }
}

// ---------------- kernel 4b: fused transpose + epilogue (i,j >= 1) --------------------------
// Tile (r,c): stages X[64r..][64c..] into LDS (f32), writes out[orow][ocol] with
// orow=64c+qq+1, ocol=64r+pp+1: v = A(orow,ocol) * (X[orow-1][orow-1] - X[ocol-1][orow-1]).
__global__ __launch_bounds__(256) void k_xtepi(const double* __restrict__ Mg,
                                               const float* __restrict__ sc,
                                               const double* __restrict__ mb,
                                               const int* __restrict__ nb,
                                               const double* __restrict__ Dg,
                                               float* __restrict__ out) {
    int b = blockIdx.y, t = blockIdx.x;
    int r = t & 3, c = t >> 2;
    const double* M = Mg + (size_t)b * S * S;
    __shared__ float L[64][65];
    __shared__ double sdg[64];
    int tid = threadIdx.x;
    int cc = tid & 63;
    #pragma unroll
    for (int rep = 0; rep < 16; ++rep) {
        int rr = rep * 4 + (tid >> 6);
        L[rr][cc] = (float)M[(size_t)(64 * r + rr) * S + 64 * c + cc];
    }
    if (tid < 64) sdg[tid] = Dg[(size_t)b * S + 64 * c + tid];
    __syncthreads();
    int n = nb[b];
    float m = (float)mb[b];
    int pp = tid & 63;
    #pragma unroll
    for (int rep = 0; rep < 16; ++rep) {
        int qq = rep * 4 + (tid >> 6);
        int orow = 64 * c + qq + 1, ocol = 64 * r + pp + 1;
        if (orow < 256 && ocol < 256) {
            float v = 0.0f;
            if (orow <= n && ocol <= n) {
                double A = (double)expf(sc[((size_t)b * S + orow) * S + ocol] - m);
                v = (float)(A * (sdg[qq] - (double)L[pp][qq]));
            }
            out[((size_t)b * S + orow) * S + ocol] = v;
        }
    }
}

// ---------------- launcher ----------------
extern "C" void kernel_launch(void* const* d_in, const int* in_sizes, int n_in,
                              void* d_out, int out_size, void* d_ws, size_t ws_size,
                              hipStream_t stream) {
    (void)in_sizes; (void)n_in; (void)out_size; (void)ws_size;
    const float* sc = (const float*)d_in[0];
    const unsigned char* mk = (const unsigned char*)d_in[1];
    double* ws = (double*)d_ws;

    double* M  = ws;                                 // B*256*256
    double* mb = M + (size_t)BB * S * S;             // B doubles
    int*    nb = (int*)(mb + BB);                    // B ints
    double* Dg = mb + 2 * BB;                        // B*256 doubles
    float*  partial = (float*)Dg;                    // aliases Dg (consumed before Dg written)
    float*  out = (float*)d_out;

    k_max<<<dim3(8, BB), 256, 0, stream>>>(sc, partial);
    k_n<<<BB, 256, 0, stream>>>(mk, partial, mb, nb);
    k_build<<<dim3(64, BB), 256, 0, stream>>>(sc, mb, nb, M);
    for (int kb = 0; kb < 4; ++kb)
        k_step<<<BB, 512, 0, stream>>>(M, kb);
    k_diag<<<BB, 256, 0, stream>>>(M, sc, mb, nb, Dg, out);
    k_xtepi<<<dim3(16, BB), 256, 0, stream>>>(M, sc, mb, nb, Dg, out);
}